// Round 8
// baseline (65.105 us; speedup 1.0000x reference)
//
#include <hip/hip_runtime.h>
#include <math.h>

#define NPTS 16384
#define HALF 8192
#define NB   32
#define NA   4
#define NC   256
#define KNN  32
#define NROW 128   // NB*NA
#define CAP  1024

// ws layout (float offsets)
#define OFF_LF      0        // 128*256
#define OFF_QKV     32768    // 128*768 (agent-atomic access)
#define OFF_RESLIN  131072   // 128*256 (agent-atomic access)
#define OFF_POSLIN  163840   // 128*256 (agent-atomic access)
#define OFF_POSST   196608   // 512     (agent-atomic access)
#define OFF_GLIN    197120   // 128*256 (agent-atomic access)
#define OFF_GST     229888   // 512     (agent-atomic access)
#define OFF_PROBLIN 230400   // 1152    (agent-atomic access)
#define OFF_CAND    231552   // 128 rows * 64 * ull = 16384 floats (agent-atomic access)
#define OFF_CNT     247936   // [0..127] row cnt (mod-2, self-healing) | [128] qkv | [129] res | [130] out

typedef unsigned long long ull;

#define AST(p, v)  __hip_atomic_store((p), (v), __ATOMIC_RELAXED, __HIP_MEMORY_SCOPE_AGENT)
#define ALD(p)     __hip_atomic_load((p), __ATOMIC_RELAXED, __HIP_MEMORY_SCOPE_AGENT)
#define AINC_REL(p) __hip_atomic_fetch_add((p), 1u, __ATOMIC_RELEASE, __HIP_MEMORY_SCOPE_AGENT)
#define ALD_ACQ(p) __hip_atomic_load((p), __ATOMIC_ACQUIRE, __HIP_MEMORY_SCOPE_AGENT)

// ========== K1: knn halves -> IC handshake -> winner merges + gathers + maxpools ==========
// Block 0 also resets K2's phase counters (safe: K1 fully precedes K2 in stream order).
__global__ __launch_bounds__(512) void knn_gather_kernel(
    const float* __restrict__ a_points, const float* __restrict__ sa_xyz,
    const float* __restrict__ sa_x,
    ull* __restrict__ cand, unsigned int* __restrict__ cnt,
    float* __restrict__ lf)
{
  const int blk  = blockIdx.x;     // row*2 + half
  const int row  = blk >> 1;       // b*4 + a
  const int half = blk & 1;
  const int b    = row >> 2;
  const int t    = threadIdx.x;

  if (blk == 0 && t < 3) AST(&cnt[NROW + t], 0u);   // reset qkv/res/out counters each replay

  __shared__ float s_T;
  __shared__ int   s_m;
  __shared__ int   s_winflag;
  __shared__ ull   s_cand[CAP];    // 8 KB; aliased as 512 floats for minima
  __shared__ ull   s64[64];
  __shared__ int   s_top[KNN];
  __shared__ float s_lf2[2][NC];
  float* smin = (float*)s_cand;

  const float ax = a_points[row*3 + 0];
  const float ay = a_points[row*3 + 1];
  const float az = a_points[row*3 + 2];
  const float* __restrict__ xyz = sa_xyz + (size_t)b * NPTS * 3 + (size_t)half * HALF * 3;

  // ---- distances: 16/thread, registers only ----
  float d[16];
#pragma unroll
  for (int j = 0; j < 16; ++j) {
    const int n = t + 512*j;
    const float dx = xyz[n*3+0] - ax;
    const float dy = xyz[n*3+1] - ay;
    const float dz = xyz[n*3+2] - az;
    d[j] = dx*dx + dy*dy + dz*dz;
  }
  float mn = d[0];
#pragma unroll
  for (int j = 1; j < 16; ++j) mn = fminf(mn, d[j]);
  if (t == 0) s_m = 0;
  smin[t] = mn;
  __syncthreads();

  // wave 0: binary search 32nd-smallest of the 512 per-thread minima (bits monotone, d>=0)
  if (t < 64) {
    unsigned v[8];
#pragma unroll
    for (int q = 0; q < 8; ++q) v[q] = __float_as_uint(smin[t + 64*q]);
    unsigned lo = 0u, hi = 0x7f7fffffu;
    while (lo < hi) {
      const unsigned mid = lo + ((hi - lo) >> 1);
      int c2 = 0;
#pragma unroll
      for (int q = 0; q < 8; ++q) c2 += (int)__popcll(__ballot(v[q] <= mid));
      if (c2 >= KNN) hi = mid; else lo = mid + 1;
    }
    if (t == 0) s_T = __uint_as_float(lo);
  }
  __syncthreads();
  const float T = s_T;   // count(d<=T) >= 32, superset of local top-32

#pragma unroll
  for (int j = 0; j < 16; ++j) {
    if (d[j] <= T) {
      const int pos = atomicAdd(&s_m, 1);
      if (pos < CAP)
        s_cand[pos] = ((ull)__float_as_uint(d[j]) << 32) | (unsigned)(half*HALF + t + 512*j);
    }
  }
  __syncthreads();
  const int m = (s_m < CAP) ? s_m : CAP;

  // exact lex rank on packed (dist,idx) = numeric ull order; agent-store sorted top-32
  for (int c2 = t; c2 < m; c2 += 512) {
    const ull me = s_cand[c2];
    int rank = 0;
    for (int j = 0; j < m; ++j) rank += (s_cand[j] < me);
    if (rank < KNN) AST(&cand[(size_t)row*64 + half*KNN + rank], me);
  }
  __syncthreads();   // drains vmcnt across all waves before the arrival mark

  // ---- arrival: 2 increments/row/replay; poison 0xAAAAAAAA is even -> last arriver wins ----
  if (t == 0) {
    const unsigned old = atomicAdd(&cnt[row], 1u);
    s_winflag = (((old + 1u) & 1u) == 0u);
  }
  __syncthreads();
  if (!s_winflag) return;

  // ---- winner: read both halves from IC ----
  if (t < 64) s64[t] = ALD(&cand[(size_t)row*64 + t]);
  __syncthreads();
  if (t < 64) {
    const ull me = s64[t];
    int rank = 0;
#pragma unroll
    for (int j = 0; j < 64; ++j) rank += (s64[j] < me);
    if (rank < KNN) s_top[rank] = (int)(unsigned)(me & 0xffffffffu);
  }
  __syncthreads();

  // ---- gather + maxpool ----
  {
    const int c = t & 255, h = t >> 8;
    const float* __restrict__ xb = sa_x + (size_t)b * NPTS * NC;
    float acc = -3.0e38f;
#pragma unroll
    for (int r2 = 0; r2 < 16; ++r2)
      acc = fmaxf(acc, xb[(size_t)s_top[h*16 + r2] * NC + c]);
    s_lf2[h][c] = acc;
  }
  __syncthreads();
  if (t < NC)
    lf[(size_t)row * NC + t] = fmaxf(s_lf2[0][t], s_lf2[1][t]);
}

// ========== K2: spin-fused lin1(96+2) -> attn(32) -> final(32, winner does out) ==========
// 162 blocks <= 256 CUs: all resident, spins always resolve. Counters reset by K1.
__global__ __launch_bounds__(256) void rest_kernel(
    const float* __restrict__ lf, const float* __restrict__ a_points,
    const float* __restrict__ qkv_W,
    const float* __restrict__ pos_W, const float* __restrict__ pos_b,
    const float* __restrict__ pos_gamma, const float* __restrict__ pos_beta,
    const float* __restrict__ g_W, const float* __restrict__ g_gamma, const float* __restrict__ g_beta,
    const float* __restrict__ res_W, const float* __restrict__ res_b,
    const float* __restrict__ res_gamma, const float* __restrict__ res_beta,
    const float* __restrict__ prob_W,
    const float* __restrict__ prob_gamma, const float* __restrict__ prob_beta,
    float* __restrict__ qkv, float* __restrict__ pos_lin, float* __restrict__ pos_stats,
    float* __restrict__ g_lin, float* __restrict__ g_stats,
    float* __restrict__ res_lin, float* __restrict__ prob_lin,
    unsigned int* __restrict__ cnt, float* __restrict__ out)
{
  const int blk = blockIdx.x;
  const int t   = threadIdx.x;
  unsigned int* cnt_qkv = &cnt[NROW + 0];
  unsigned int* cnt_res = &cnt[NROW + 1];
  unsigned int* cnt_out = &cnt[NROW + 2];

  if (blk < 96) {
    // ---- qkv GEMM tile: 8 rowtiles(16) x 12 otiles(64) ----
    const int r0 = (blk / 12) * 16;
    const int o0 = (blk % 12) * 64;
    const int ot = t & 63;
    const int rt = t >> 6;
    const int o  = o0 + ot;
    const float* __restrict__ wrow = qkv_W + (size_t)o * NC;
    const float* __restrict__ l0p  = lf + (size_t)(r0 + rt*4) * NC;
    float acc0 = 0.f, acc1 = 0.f, acc2 = 0.f, acc3 = 0.f;
    for (int c = 0; c < NC; c += 4) {
      const float4 w4 = *(const float4*)(wrow + c);
      const float4 l0 = *(const float4*)(l0p + c);
      const float4 l1 = *(const float4*)(l0p + NC + c);
      const float4 l2 = *(const float4*)(l0p + 2*NC + c);
      const float4 l3 = *(const float4*)(l0p + 3*NC + c);
      acc0 = fmaf(l0.x,w4.x,acc0); acc0 = fmaf(l0.y,w4.y,acc0); acc0 = fmaf(l0.z,w4.z,acc0); acc0 = fmaf(l0.w,w4.w,acc0);
      acc1 = fmaf(l1.x,w4.x,acc1); acc1 = fmaf(l1.y,w4.y,acc1); acc1 = fmaf(l1.z,w4.z,acc1); acc1 = fmaf(l1.w,w4.w,acc1);
      acc2 = fmaf(l2.x,w4.x,acc2); acc2 = fmaf(l2.y,w4.y,acc2); acc2 = fmaf(l2.z,w4.z,acc2); acc2 = fmaf(l2.w,w4.w,acc2);
      acc3 = fmaf(l3.x,w4.x,acc3); acc3 = fmaf(l3.y,w4.y,acc3); acc3 = fmaf(l3.z,w4.z,acc3); acc3 = fmaf(l3.w,w4.w,acc3);
    }
    const int r = r0 + rt*4;
    AST(&qkv[(size_t)(r+0)*768 + o], acc0);
    AST(&qkv[(size_t)(r+1)*768 + o], acc1);
    AST(&qkv[(size_t)(r+2)*768 + o], acc2);
    AST(&qkv[(size_t)(r+3)*768 + o], acc3);
    __syncthreads();
    if (t == 0) AINC_REL(cnt_qkv);

  } else if (blk < 98) {
    // ---- pos (blk 96) / g (blk 97) linear + stats ----
    __shared__ float apts[NROW*3];
    for (int i = t; i < NROW*3; i += 256) apts[i] = a_points[i];
    __syncthreads();
    const int c = t;
    if (blk == 96) {
      const float w0 = pos_W[c*3+0], w1 = pos_W[c*3+1], w2 = pos_W[c*3+2];
      const float bb = pos_b[c];
      float sum = 0.f, sumsq = 0.f;
      for (int b = 0; b < NB; ++b) {
        float gx=0.f, gy=0.f, gz=0.f;
#pragma unroll
        for (int a = 0; a < NA; ++a) {
          gx += apts[(b*NA+a)*3+0];
          gy += apts[(b*NA+a)*3+1];
          gz += apts[(b*NA+a)*3+2];
        }
        gx *= 0.25f; gy *= 0.25f; gz *= 0.25f;
#pragma unroll
        for (int a = 0; a < NA; ++a) {
          const float v = (apts[(b*NA+a)*3+0]-gx)*w0
                        + (apts[(b*NA+a)*3+1]-gy)*w1
                        + (apts[(b*NA+a)*3+2]-gz)*w2 + bb;
          AST(&pos_lin[(b*NA+a)*NC + c], v);
          sum += v; sumsq += v*v;
        }
      }
      AST(&pos_stats[c], sum); AST(&pos_stats[NC + c], sumsq);
    } else {
      const float w0 = g_W[c*3+0], w1 = g_W[c*3+1], w2 = g_W[c*3+2];
      float sum = 0.f, sumsq = 0.f;
      for (int r = 0; r < NROW; ++r) {
        const float v = apts[r*3+0]*w0 + apts[r*3+1]*w1 + apts[r*3+2]*w2;
        AST(&g_lin[r*NC + c], v);
        sum += v; sumsq += v*v;
      }
      AST(&g_stats[c], sum); AST(&g_stats[NC + c], sumsq);
    }
    __syncthreads();
    if (t == 0) AINC_REL(cnt_qkv);

  } else if (blk < 130) {
    // ---- attn for batch b = blk-98: wait for all 98 producers ----
    const int b = blk - 98;
    __shared__ float av_s[NA][NC];
    __shared__ int s_go;
    if (t == 0) {
      while (ALD_ACQ(cnt_qkv) < 98u) __builtin_amdgcn_s_sleep(16);
      s_go = 1;
    }
    __syncthreads();
    (void)s_go;

    const int c = t;
    const float psum = ALD(&pos_stats[c]);
    const float psq  = ALD(&pos_stats[NC + c]);
    const float pmean = psum * (1.0f/NROW);
    const float pvar  = psq * (1.0f/NROW) - pmean*pmean;
    const float prstd = 1.0f / sqrtf(pvar + 1e-5f);
    const float pga = pos_gamma[c], pbe = pos_beta[c];

    float q[NA], k[NA], vv[NA];
#pragma unroll
    for (int a = 0; a < NA; ++a) {
      const int row = b*NA + a;
      const float p = pga * (ALD(&pos_lin[(size_t)row*NC + c]) - pmean) * prstd + pbe;
      q[a]  = ALD(&qkv[(size_t)row*768 +       c]) + p;
      k[a]  = ALD(&qkv[(size_t)row*768 + 256 + c]) + p;
      vv[a] = ALD(&qkv[(size_t)row*768 + 512 + c]) + p;
    }
    float s[NA][NA];
#pragma unroll
    for (int m = 0; m < NA; ++m) {
#pragma unroll
      for (int n = 0; n < NA; ++n) {
        float p = q[m]*k[n];
#pragma unroll
        for (int off = 1; off < 64; off <<= 1) p += __shfl_xor(p, off);
        s[m][n] = p * 0.125f;   // 1/sqrt(64)
      }
    }
#pragma unroll
    for (int m = 0; m < NA; ++m) {
      const float mx = fmaxf(fmaxf(s[m][0], s[m][1]), fmaxf(s[m][2], s[m][3]));
      const float e0 = expf(s[m][0]-mx), e1 = expf(s[m][1]-mx);
      const float e2 = expf(s[m][2]-mx), e3 = expf(s[m][3]-mx);
      const float inv = 1.0f / (e0+e1+e2+e3);
      av_s[m][c] = (e0*vv[0] + e1*vv[1] + e2*vv[2] + e3*vv[3]) * inv;
    }
    __syncthreads();

    const float* __restrict__ wrow = res_W + (size_t)c * NC;
    float r0=0.f, r1=0.f, r2=0.f, r3=0.f;
    for (int cc = 0; cc < NC; cc += 4) {
      const float4 w4 = *(const float4*)(wrow + cc);
      const float4 v0 = *(const float4*)&av_s[0][cc];
      const float4 v1 = *(const float4*)&av_s[1][cc];
      const float4 v2 = *(const float4*)&av_s[2][cc];
      const float4 v3 = *(const float4*)&av_s[3][cc];
      r0 = fmaf(v0.x,w4.x,r0); r0 = fmaf(v0.y,w4.y,r0); r0 = fmaf(v0.z,w4.z,r0); r0 = fmaf(v0.w,w4.w,r0);
      r1 = fmaf(v1.x,w4.x,r1); r1 = fmaf(v1.y,w4.y,r1); r1 = fmaf(v1.z,w4.z,r1); r1 = fmaf(v1.w,w4.w,r1);
      r2 = fmaf(v2.x,w4.x,r2); r2 = fmaf(v2.y,w4.y,r2); r2 = fmaf(v2.z,w4.z,r2); r2 = fmaf(v2.w,w4.w,r2);
      r3 = fmaf(v3.x,w4.x,r3); r3 = fmaf(v3.y,w4.y,r3); r3 = fmaf(v3.z,w4.z,r3); r3 = fmaf(v3.w,w4.w,r3);
    }
    const float bias = res_b[c];
    AST(&res_lin[(size_t)(b*NA+0)*NC + c], r0 + bias);
    AST(&res_lin[(size_t)(b*NA+1)*NC + c], r1 + bias);
    AST(&res_lin[(size_t)(b*NA+2)*NC + c], r2 + bias);
    AST(&res_lin[(size_t)(b*NA+3)*NC + c], r3 + bias);
    __syncthreads();
    if (t == 0) AINC_REL(cnt_res);

  } else {
    // ---- final for batch b = blk-130: wait for all 32 attn blocks ----
    const int b = blk - 130;
    __shared__ float feat_s[NA][2 * NC];
    __shared__ int   s_winflag;
    __shared__ float s_prob[NROW*9];
    __shared__ float pmn[9], prs[9];
    __shared__ int s_go;
    if (t == 0) {
      while (ALD_ACQ(cnt_res) < 32u) __builtin_amdgcn_s_sleep(16);
      s_go = 1;
    }
    __syncthreads();
    (void)s_go;

    const int c = t;
    float rsum = 0.f, rss = 0.f;
#pragma unroll 16
    for (int row = 0; row < NROW; ++row) {
      const float v = ALD(&res_lin[(size_t)row*NC + c]);
      rsum += v; rss += v*v;
    }
    const float rmean = rsum * (1.0f/NROW);
    const float rvar  = rss * (1.0f/NROW) - rmean*rmean;
    const float rrstd = 1.0f / sqrtf(rvar + 1e-5f);
    const float rg = res_gamma[c], rb = res_beta[c];

    const float gmean = ALD(&g_stats[c]) * (1.0f/NROW);
    const float gvar  = ALD(&g_stats[NC+c]) * (1.0f/NROW) - gmean*gmean;
    const float grstd = 1.0f / sqrtf(gvar + 1e-5f);
    const float gg = g_gamma[c], gb = g_beta[c];

    float gm = -3.0e38f;
#pragma unroll
    for (int a = 0; a < NA; ++a) {
      const int row = b*NA + a;
      gm = fmaxf(gm, gg * (ALD(&g_lin[(size_t)row*NC + c]) - gmean) * grstd + gb);
    }
#pragma unroll
    for (int a = 0; a < NA; ++a) {
      const int row = b*NA + a;
      const float resv = rg * (ALD(&res_lin[(size_t)row*NC + c]) - rmean) * rrstd + rb;
      feat_s[a][c]      = lf[(size_t)row*NC + c] + resv;
      feat_s[a][NC + c] = gm;
    }
    __syncthreads();

    const int m = t >> 6, lane = t & 63;
    for (int j = 0; j < 9; ++j) {
      float p = 0.f;
#pragma unroll
      for (int k2 = 0; k2 < 8; ++k2) {
        const int cc = lane + 64*k2;
        p = fmaf(feat_s[m][cc], prob_W[j*2*NC + cc], p);
      }
#pragma unroll
      for (int off = 1; off < 64; off <<= 1) p += __shfl_xor(p, off);
      if (lane == 0) AST(&prob_lin[(b*NA+m)*9 + j], p);
    }
    __syncthreads();

    // counter reset to 0 by K1 each replay -> 32nd (last) arriver wins, poison-proof
    if (t == 0) {
      const unsigned old = AINC_REL(cnt_out);
      s_winflag = ((old + 1u) == 32u);
    }
    __syncthreads();
    if (!s_winflag) return;

    for (int i = t; i < NROW*9; i += 256) s_prob[i] = ALD(&prob_lin[i]);
    __syncthreads();
    if (t < 9) {
      float s = 0.f, ss = 0.f;
      for (int i = 0; i < NROW; ++i) { const float v = s_prob[i*9+t]; s += v; ss += v*v; }
      const float mm = s * (1.0f/NROW);
      const float va = ss * (1.0f/NROW) - mm*mm;
      pmn[t] = mm; prs[t] = 1.0f / sqrtf(va + 1e-5f);
    }
    __syncthreads();
    for (int i = t; i < NROW*9; i += 256) {
      const int j = i % 9;
      out[i] = prob_gamma[j] * (s_prob[i] - pmn[j]) * prs[j] + prob_beta[j];
    }
  }
}

extern "C" void kernel_launch(void* const* d_in, const int* in_sizes, int n_in,
                              void* d_out, int out_size, void* d_ws, size_t ws_size,
                              hipStream_t stream) {
  const float* a_points  = (const float*)d_in[0];
  const float* sa_x      = (const float*)d_in[1];
  const float* sa_xyz    = (const float*)d_in[2];
  // d_in[3] xyz_raw: unused by the reference
  const float* g_W       = (const float*)d_in[4];
  const float* g_gamma   = (const float*)d_in[5];
  const float* g_beta    = (const float*)d_in[6];
  const float* qkv_W     = (const float*)d_in[7];
  const float* pos_W     = (const float*)d_in[8];
  const float* pos_b     = (const float*)d_in[9];
  const float* pos_gamma = (const float*)d_in[10];
  const float* pos_beta  = (const float*)d_in[11];
  const float* res_W     = (const float*)d_in[12];
  const float* res_b     = (const float*)d_in[13];
  const float* res_gamma = (const float*)d_in[14];
  const float* res_beta  = (const float*)d_in[15];
  const float* prob_W    = (const float*)d_in[16];
  const float* prob_gamma= (const float*)d_in[17];
  const float* prob_beta = (const float*)d_in[18];
  float* ws  = (float*)d_ws;
  float* out = (float*)d_out;
  unsigned int* cnt = (unsigned int*)(ws + OFF_CNT);

  knn_gather_kernel<<<256, 512, 0, stream>>>(a_points, sa_xyz, sa_x,
      (ull*)(ws + OFF_CAND), cnt, ws + OFF_LF);
  rest_kernel<<<162, 256, 0, stream>>>(ws + OFF_LF, a_points, qkv_W,
      pos_W, pos_b, pos_gamma, pos_beta,
      g_W, g_gamma, g_beta,
      res_W, res_b, res_gamma, res_beta,
      prob_W, prob_gamma, prob_beta,
      ws + OFF_QKV, ws + OFF_POSLIN, ws + OFF_POSST,
      ws + OFF_GLIN, ws + OFF_GST,
      ws + OFF_RESLIN, ws + OFF_PROBLIN,
      cnt, out);
}

// Round 9
// 57.295 us; speedup vs baseline: 1.1363x; 1.1363x over previous
//
#include <hip/hip_runtime.h>
#include <math.h>

#define NPTS 16384
#define HALF 8192
#define NB   32
#define NA   4
#define NC   256
#define KNN  32
#define NROW 128   // NB*NA
#define CAP  1024

// ws layout (float offsets)
#define OFF_LF      0        // 128*256
#define OFF_QKV     32768    // 128*768
#define OFF_RESLIN  131072   // 128*256
#define OFF_POSLIN  163840   // 128*256
#define OFF_POSST   196608   // 512
#define OFF_GLIN    197120   // 128*256
#define OFF_GST     229888   // 512
#define OFF_PROBLIN 230400   // 1152 (agent-atomic access)
#define OFF_CAND    231552   // 128 rows * 64 * ull (agent-atomic access)
#define OFF_CNT     247936   // [0..127] row cnt (mod-2, poison-proof) | [128] out cnt (reset by K1)

typedef unsigned long long ull;
#define AST(p, v)  __hip_atomic_store((p), (v), __ATOMIC_RELAXED, __HIP_MEMORY_SCOPE_AGENT)
#define ALD(p)     __hip_atomic_load((p), __ATOMIC_RELAXED, __HIP_MEMORY_SCOPE_AGENT)

// ========== K1: 256 knn-half blocks (winner merges+gathers) + pos blk 256 + g blk 257 ==========
__global__ __launch_bounds__(512) void knn_gather_kernel(
    const float* __restrict__ a_points, const float* __restrict__ sa_xyz,
    const float* __restrict__ sa_x,
    const float* __restrict__ pos_W, const float* __restrict__ pos_b,
    const float* __restrict__ g_W,
    ull* __restrict__ cand, unsigned int* __restrict__ cnt,
    float* __restrict__ lf,
    float* __restrict__ pos_lin, float* __restrict__ pos_stats,
    float* __restrict__ g_lin, float* __restrict__ g_stats)
{
  const int blk = blockIdx.x;
  const int t   = threadIdx.x;

  if (blk >= 256) {
    // ---- pos (256) / g (257): depend only on a_points; overlap under knn ----
    if (blk == 256 && t == 0) AST(&cnt[NROW], 0u);   // exact reset of final's winner counter
    __shared__ float apts[NROW * 3];
    for (int i = t; i < NROW*3; i += 512) apts[i] = a_points[i];
    __syncthreads();
    if (t < NC) {
      const int c = t;
      if (blk == 256) {
        const float w0 = pos_W[c*3+0], w1 = pos_W[c*3+1], w2 = pos_W[c*3+2];
        const float bb = pos_b[c];
        float sum = 0.f, sumsq = 0.f;
        for (int b = 0; b < NB; ++b) {
          float gx=0.f, gy=0.f, gz=0.f;
#pragma unroll
          for (int a = 0; a < NA; ++a) {
            gx += apts[(b*NA+a)*3+0];
            gy += apts[(b*NA+a)*3+1];
            gz += apts[(b*NA+a)*3+2];
          }
          gx *= 0.25f; gy *= 0.25f; gz *= 0.25f;
#pragma unroll
          for (int a = 0; a < NA; ++a) {
            const float v = (apts[(b*NA+a)*3+0]-gx)*w0
                          + (apts[(b*NA+a)*3+1]-gy)*w1
                          + (apts[(b*NA+a)*3+2]-gz)*w2 + bb;
            pos_lin[(b*NA+a)*NC + c] = v;
            sum += v; sumsq += v*v;
          }
        }
        pos_stats[c] = sum; pos_stats[NC + c] = sumsq;
      } else {
        const float w0 = g_W[c*3+0], w1 = g_W[c*3+1], w2 = g_W[c*3+2];
        float sum = 0.f, sumsq = 0.f;
        for (int r = 0; r < NROW; ++r) {
          const float v = apts[r*3+0]*w0 + apts[r*3+1]*w1 + apts[r*3+2]*w2;
          g_lin[r*NC + c] = v;
          sum += v; sumsq += v*v;
        }
        g_stats[c] = sum; g_stats[NC + c] = sumsq;
      }
    }
    return;
  }

  const int row  = blk >> 1;       // b*4 + a
  const int half = blk & 1;
  const int b    = row >> 2;

  __shared__ float s_T;
  __shared__ int   s_m;
  __shared__ int   s_winflag;
  __shared__ ull   s_cand[CAP];    // 8 KB; aliased as 512 floats for minima
  __shared__ ull   s64[64];
  __shared__ int   s_top[KNN];
  __shared__ float s_lf2[2][NC];
  float* smin = (float*)s_cand;

  const float ax = a_points[row*3 + 0];
  const float ay = a_points[row*3 + 1];
  const float az = a_points[row*3 + 2];
  const float* __restrict__ xyz = sa_xyz + (size_t)b * NPTS * 3 + (size_t)half * HALF * 3;

  // ---- distances: 16/thread, registers only ----
  float d[16];
#pragma unroll
  for (int j = 0; j < 16; ++j) {
    const int n = t + 512*j;
    const float dx = xyz[n*3+0] - ax;
    const float dy = xyz[n*3+1] - ay;
    const float dz = xyz[n*3+2] - az;
    d[j] = dx*dx + dy*dy + dz*dz;
  }
  float mn = d[0];
#pragma unroll
  for (int j = 1; j < 16; ++j) mn = fminf(mn, d[j]);
  if (t == 0) s_m = 0;
  smin[t] = mn;
  __syncthreads();

  // wave 0: binary search 32nd-smallest of the 512 per-thread minima (bits monotone, d>=0)
  if (t < 64) {
    unsigned v[8];
#pragma unroll
    for (int q = 0; q < 8; ++q) v[q] = __float_as_uint(smin[t + 64*q]);
    unsigned lo = 0u, hi = 0x7f7fffffu;
    while (lo < hi) {
      const unsigned mid = lo + ((hi - lo) >> 1);
      int c2 = 0;
#pragma unroll
      for (int q = 0; q < 8; ++q) c2 += (int)__popcll(__ballot(v[q] <= mid));
      if (c2 >= KNN) hi = mid; else lo = mid + 1;
    }
    if (t == 0) s_T = __uint_as_float(lo);
  }
  __syncthreads();
  const float T = s_T;   // count(d<=T) >= 32, superset of local top-32

#pragma unroll
  for (int j = 0; j < 16; ++j) {
    if (d[j] <= T) {
      const int pos = atomicAdd(&s_m, 1);
      if (pos < CAP)
        s_cand[pos] = ((ull)__float_as_uint(d[j]) << 32) | (unsigned)(half*HALF + t + 512*j);
    }
  }
  __syncthreads();
  const int m = (s_m < CAP) ? s_m : CAP;

  // exact lex rank on packed (dist,idx) = numeric ull order; agent-store sorted top-32 to IC
  for (int c2 = t; c2 < m; c2 += 512) {
    const ull me = s_cand[c2];
    int rank = 0;
    for (int j = 0; j < m; ++j) rank += (s_cand[j] < me);
    if (rank < KNN) AST(&cand[(size_t)row*64 + half*KNN + rank], me);
  }
  __syncthreads();   // drains vmcnt across all waves before the arrival mark

  // ---- arrival: 2 increments/row/replay; poison is even -> last arriver wins (exact) ----
  if (t == 0) {
    const unsigned old = atomicAdd(&cnt[row], 1u);
    s_winflag = (((old + 1u) & 1u) == 0u);
  }
  __syncthreads();
  if (!s_winflag) return;

  // ---- winner: read both halves from IC ----
  if (t < 64) s64[t] = ALD(&cand[(size_t)row*64 + t]);
  __syncthreads();
  if (t < 64) {
    const ull me = s64[t];
    int rank = 0;
#pragma unroll
    for (int j = 0; j < 64; ++j) rank += (s64[j] < me);
    if (rank < KNN) s_top[rank] = (int)(unsigned)(me & 0xffffffffu);
  }
  __syncthreads();

  // ---- gather + maxpool ----
  {
    const int c = t & 255, h = t >> 8;
    const float* __restrict__ xb = sa_x + (size_t)b * NPTS * NC;
    float acc = -3.0e38f;
#pragma unroll
    for (int r2 = 0; r2 < 16; ++r2)
      acc = fmaxf(acc, xb[(size_t)s_top[h*16 + r2] * NC + c]);
    s_lf2[h][c] = acc;
  }
  __syncthreads();
  if (t < NC)
    lf[(size_t)row * NC + t] = fmaxf(s_lf2[0][t], s_lf2[1][t]);
}

// ========== K2: qkv GEMM, 96 tiles (8 rowtiles x 12 otiles) ==========
__global__ __launch_bounds__(256) void lin1_kernel(
    const float* __restrict__ lf, const float* __restrict__ qkv_W,
    float* __restrict__ qkv)
{
  const int blk = blockIdx.x;
  const int r0 = (blk / 12) * 16;
  const int o0 = (blk % 12) * 64;
  const int ot = threadIdx.x & 63;
  const int rt = threadIdx.x >> 6;
  const int o  = o0 + ot;
  const float* __restrict__ wrow = qkv_W + (size_t)o * NC;
  const float* __restrict__ l0p  = lf + (size_t)(r0 + rt*4) * NC;
  float acc0 = 0.f, acc1 = 0.f, acc2 = 0.f, acc3 = 0.f;
  for (int c = 0; c < NC; c += 4) {
    const float4 w4 = *(const float4*)(wrow + c);
    const float4 l0 = *(const float4*)(l0p + c);
    const float4 l1 = *(const float4*)(l0p + NC + c);
    const float4 l2 = *(const float4*)(l0p + 2*NC + c);
    const float4 l3 = *(const float4*)(l0p + 3*NC + c);
    acc0 = fmaf(l0.x,w4.x,acc0); acc0 = fmaf(l0.y,w4.y,acc0); acc0 = fmaf(l0.z,w4.z,acc0); acc0 = fmaf(l0.w,w4.w,acc0);
    acc1 = fmaf(l1.x,w4.x,acc1); acc1 = fmaf(l1.y,w4.y,acc1); acc1 = fmaf(l1.z,w4.z,acc1); acc1 = fmaf(l1.w,w4.w,acc1);
    acc2 = fmaf(l2.x,w4.x,acc2); acc2 = fmaf(l2.y,w4.y,acc2); acc2 = fmaf(l2.z,w4.z,acc2); acc2 = fmaf(l2.w,w4.w,acc2);
    acc3 = fmaf(l3.x,w4.x,acc3); acc3 = fmaf(l3.y,w4.y,acc3); acc3 = fmaf(l3.z,w4.z,acc3); acc3 = fmaf(l3.w,w4.w,acc3);
  }
  const int r = r0 + rt*4;
  qkv[(size_t)(r+0)*768 + o] = acc0;
  qkv[(size_t)(r+1)*768 + o] = acc1;
  qkv[(size_t)(r+2)*768 + o] = acc2;
  qkv[(size_t)(r+3)*768 + o] = acc3;
}

// ========== K3: attn, 128 blocks = (batch b, output-quarter qo) ==========
__global__ __launch_bounds__(256) void attn_kernel(
    const float* __restrict__ qkv, const float* __restrict__ pos_lin,
    const float* __restrict__ pos_stats,
    const float* __restrict__ pos_gamma, const float* __restrict__ pos_beta,
    const float* __restrict__ res_W, const float* __restrict__ res_b,
    float* __restrict__ res_lin)
{
  const int b  = blockIdx.x >> 2;
  const int qo = blockIdx.x & 3;
  const int t  = threadIdx.x;
  __shared__ float av_s[NA][NC];

  // phase 1: full av_s (thread = channel c); duplicated across the 4 qo-blocks (cheap)
  {
    const int c = t;
    const float pmean = pos_stats[c] * (1.0f/NROW);
    const float pvar  = pos_stats[NC + c] * (1.0f/NROW) - pmean*pmean;
    const float prstd = 1.0f / sqrtf(pvar + 1e-5f);
    const float pga = pos_gamma[c], pbe = pos_beta[c];

    float q[NA], k[NA], vv[NA];
#pragma unroll
    for (int a = 0; a < NA; ++a) {
      const int row = b*NA + a;
      const float p = pga * (pos_lin[(size_t)row*NC + c] - pmean) * prstd + pbe;
      q[a]  = qkv[(size_t)row*768 +       c] + p;
      k[a]  = qkv[(size_t)row*768 + 256 + c] + p;
      vv[a] = qkv[(size_t)row*768 + 512 + c] + p;
    }
    float s[NA][NA];
#pragma unroll
    for (int m = 0; m < NA; ++m) {
#pragma unroll
      for (int n = 0; n < NA; ++n) {
        float p = q[m]*k[n];
#pragma unroll
        for (int off = 1; off < 64; off <<= 1) p += __shfl_xor(p, off);
        s[m][n] = p * 0.125f;   // 1/sqrt(64)
      }
    }
#pragma unroll
    for (int m = 0; m < NA; ++m) {
      const float mx = fmaxf(fmaxf(s[m][0], s[m][1]), fmaxf(s[m][2], s[m][3]));
      const float e0 = expf(s[m][0]-mx), e1 = expf(s[m][1]-mx);
      const float e2 = expf(s[m][2]-mx), e3 = expf(s[m][3]-mx);
      const float inv = 1.0f / (e0+e1+e2+e3);
      av_s[m][c] = (e0*vv[0] + e1*vv[1] + e2*vv[2] + e3*vv[3]) * inv;
    }
  }
  __syncthreads();

  // phase 2: res GEMM for this quarter's 64 outputs; thread = (out ot, row rt)
  const int ot = t & 63, rt = t >> 6;
  const int o  = qo*64 + ot;
  const float* __restrict__ wrow = res_W + (size_t)o * NC;
  float acc = 0.f;
  for (int cc = 0; cc < NC; cc += 4) {
    const float4 w4 = *(const float4*)(wrow + cc);
    const float4 v4 = *(const float4*)&av_s[rt][cc];
    acc = fmaf(v4.x,w4.x,acc); acc = fmaf(v4.y,w4.y,acc);
    acc = fmaf(v4.z,w4.z,acc); acc = fmaf(v4.w,w4.w,acc);
  }
  res_lin[(size_t)(b*NA+rt)*NC + o] = acc + res_b[o];
}

// ========== K4: res-BN+add, g-BN+max, prob GEMM; exact last-arriver does prob-BN -> out ==========
__global__ __launch_bounds__(256) void final_kernel(
    const float* __restrict__ lf, const float* __restrict__ res_lin,
    const float* __restrict__ res_gamma, const float* __restrict__ res_beta,
    const float* __restrict__ g_lin, const float* __restrict__ g_stats,
    const float* __restrict__ g_gamma, const float* __restrict__ g_beta,
    const float* __restrict__ prob_W,
    const float* __restrict__ prob_gamma, const float* __restrict__ prob_beta,
    float* __restrict__ prob_lin, unsigned int* __restrict__ cnt_out,
    float* __restrict__ out)
{
  const int b = blockIdx.x;
  const int t = threadIdx.x;
  __shared__ float feat_s[NA][2 * NC];
  __shared__ int   s_winflag;
  __shared__ float s_prob[NROW*9];
  __shared__ float pmn[9], prs[9];
  const int c = t;
  float rsum = 0.f, rss = 0.f;
#pragma unroll 16
  for (int row = 0; row < NROW; ++row) {
    const float v = res_lin[(size_t)row*NC + c];
    rsum += v; rss += v*v;
  }
  const float rmean = rsum * (1.0f/NROW);
  const float rvar  = rss * (1.0f/NROW) - rmean*rmean;
  const float rrstd = 1.0f / sqrtf(rvar + 1e-5f);
  const float rg = res_gamma[c], rb = res_beta[c];

  const float gmean = g_stats[c] * (1.0f/NROW);
  const float gvar  = g_stats[NC+c] * (1.0f/NROW) - gmean*gmean;
  const float grstd = 1.0f / sqrtf(gvar + 1e-5f);
  const float gg = g_gamma[c], gb = g_beta[c];

  float gm = -3.0e38f;
#pragma unroll
  for (int a = 0; a < NA; ++a) {
    const int row = b*NA + a;
    gm = fmaxf(gm, gg * (g_lin[(size_t)row*NC + c] - gmean) * grstd + gb);
  }
#pragma unroll
  for (int a = 0; a < NA; ++a) {
    const int row = b*NA + a;
    const float resv = rg * (res_lin[(size_t)row*NC + c] - rmean) * rrstd + rb;
    feat_s[a][c]      = lf[(size_t)row*NC + c] + resv;
    feat_s[a][NC + c] = gm;
  }
  __syncthreads();

  const int m = t >> 6, lane = t & 63;
  for (int j = 0; j < 9; ++j) {
    float p = 0.f;
#pragma unroll
    for (int k2 = 0; k2 < 8; ++k2) {
      const int cc = lane + 64*k2;
      p = fmaf(feat_s[m][cc], prob_W[j*2*NC + cc], p);
    }
#pragma unroll
    for (int off = 1; off < 64; off <<= 1) p += __shfl_xor(p, off);
    if (lane == 0) AST(&prob_lin[(b*NA+m)*9 + j], p);
  }
  __syncthreads();   // drains vmcnt: this block's prob stores are at the coherence point

  // counter reset to 0 by K1 (two kernel boundaries ago) -> winner = exact 32nd arriver
  if (t == 0) {
    const unsigned old = atomicAdd(cnt_out, 1u);
    s_winflag = ((old + 1u) == 32u);
  }
  __syncthreads();
  if (!s_winflag) return;

  for (int i = t; i < NROW*9; i += 256) s_prob[i] = ALD(&prob_lin[i]);
  __syncthreads();
  if (t < 9) {
    float s = 0.f, ss = 0.f;
    for (int i = 0; i < NROW; ++i) { const float v = s_prob[i*9+t]; s += v; ss += v*v; }
    const float mm = s * (1.0f/NROW);
    const float va = ss * (1.0f/NROW) - mm*mm;
    pmn[t] = mm; prs[t] = 1.0f / sqrtf(va + 1e-5f);
  }
  __syncthreads();
  for (int i = t; i < NROW*9; i += 256) {
    const int j = i % 9;
    out[i] = prob_gamma[j] * (s_prob[i] - pmn[j]) * prs[j] + prob_beta[j];
  }
}

extern "C" void kernel_launch(void* const* d_in, const int* in_sizes, int n_in,
                              void* d_out, int out_size, void* d_ws, size_t ws_size,
                              hipStream_t stream) {
  const float* a_points  = (const float*)d_in[0];
  const float* sa_x      = (const float*)d_in[1];
  const float* sa_xyz    = (const float*)d_in[2];
  // d_in[3] xyz_raw: unused by the reference
  const float* g_W       = (const float*)d_in[4];
  const float* g_gamma   = (const float*)d_in[5];
  const float* g_beta    = (const float*)d_in[6];
  const float* qkv_W     = (const float*)d_in[7];
  const float* pos_W     = (const float*)d_in[8];
  const float* pos_b     = (const float*)d_in[9];
  const float* pos_gamma = (const float*)d_in[10];
  const float* pos_beta  = (const float*)d_in[11];
  const float* res_W     = (const float*)d_in[12];
  const float* res_b     = (const float*)d_in[13];
  const float* res_gamma = (const float*)d_in[14];
  const float* res_beta  = (const float*)d_in[15];
  const float* prob_W    = (const float*)d_in[16];
  const float* prob_gamma= (const float*)d_in[17];
  const float* prob_beta = (const float*)d_in[18];
  float* ws  = (float*)d_ws;
  float* out = (float*)d_out;
  unsigned int* cnt = (unsigned int*)(ws + OFF_CNT);

  knn_gather_kernel<<<258, 512, 0, stream>>>(a_points, sa_xyz, sa_x,
      pos_W, pos_b, g_W,
      (ull*)(ws + OFF_CAND), cnt, ws + OFF_LF,
      ws + OFF_POSLIN, ws + OFF_POSST, ws + OFF_GLIN, ws + OFF_GST);
  lin1_kernel<<<96, 256, 0, stream>>>(ws + OFF_LF, qkv_W, ws + OFF_QKV);
  attn_kernel<<<128, 256, 0, stream>>>(ws + OFF_QKV, ws + OFF_POSLIN, ws + OFF_POSST,
      pos_gamma, pos_beta, res_W, res_b, ws + OFF_RESLIN);
  final_kernel<<<NB, 256, 0, stream>>>(ws + OFF_LF, ws + OFF_RESLIN,
      res_gamma, res_beta, ws + OFF_GLIN, ws + OFF_GST, g_gamma, g_beta,
      prob_W, prob_gamma, prob_beta,
      ws + OFF_PROBLIN, cnt + NROW, out);
}